// Round 6
// baseline (464.454 us; speedup 1.0000x reference)
//
#include <hip/hip_runtime.h>
#include <math.h>

#define B  128
#define L  64
#define NS 32
#define NI 16
#define D  256

typedef __attribute__((ext_vector_type(8))) short bf16x8;
typedef __attribute__((ext_vector_type(4))) float f32x4;

__device__ __forceinline__ float wave_reduce_sum(float v) {
#pragma unroll
  for (int off = 32; off; off >>= 1) v += __shfl_xor(v, off, 64);
  return v;
}
__device__ __forceinline__ float wave_reduce_max(float v) {
#pragma unroll
  for (int off = 32; off; off >>= 1) v = fmaxf(v, __shfl_xor(v, off, 64));
  return v;
}

// packed RTNE f32x2 -> bf16x2 (single HW instr)
__device__ __forceinline__ uint cvt_pk_bf16(float a, float b) {
  uint r;
  asm("v_cvt_pk_bf16_f32 %0, %1, %2" : "=v"(r) : "v"(a), "v"(b));
  return r;  // lo16 = bf16(a), hi16 = bf16(b)
}
// float4 -> hi-pair u32x2 + lo-pair u32x2 (x ~= hi + lo, residual ~2^-17)
__device__ __forceinline__ void split4(float4 v, uint2& h, uint2& lo) {
  h.x = cvt_pk_bf16(v.x, v.y);
  h.y = cvt_pk_bf16(v.z, v.w);
  float h0 = __uint_as_float(h.x << 16);
  float h1 = __uint_as_float(h.x & 0xFFFF0000u);
  float h2 = __uint_as_float(h.y << 16);
  float h3 = __uint_as_float(h.y & 0xFFFF0000u);
  lo.x = cvt_pk_bf16(v.x - h0, v.y - h1);
  lo.y = cvt_pk_bf16(v.z - h2, v.w - h3);
}

// barrier that does NOT drain vmcnt (prefetch loads stay in flight)
#define LGKM_BARRIER()                                   \
  do {                                                   \
    asm volatile("s_waitcnt lgkmcnt(0)" ::: "memory");   \
    __builtin_amdgcn_s_barrier();                        \
    asm volatile("" ::: "memory");                       \
  } while (0)

// swizzled ushort index into a [128 rows][64 cols] bf16 LDS tile, 128B rows.
// XOR of (row&7)<<4: ushort4/uint2 writes and b128 reads both bank-uniform.
__device__ __forceinline__ int swzA(int row, int kcol) {
  int byte = (row << 7) + (kcol << 1);
  byte ^= (row & 7) << 4;
  return byte >> 1;
}

// ---------------------------------------------------------------------------
// K1: per (b,l): a_words = mean(x); logits = w_route_ws[l] . x; softmax;
//     wlsT[l][s][b] = c_ws * a_words.
// ---------------------------------------------------------------------------
__global__ __launch_bounds__(256) void k1_route_words(
    const float* __restrict__ tf, const float* __restrict__ wr,
    float* __restrict__ wlsT, float* __restrict__ a_words) {
  int bl = blockIdx.x;
  int b  = bl >> 6;
  int l  = bl & (L - 1);
  int t  = threadIdx.x;
  int wave = t >> 6, lane = t & 63;
  __shared__ float sx[D];
  __shared__ float slog[NS];
  __shared__ float s_aw;
  sx[t] = tf[bl * D + t];
  __syncthreads();
  const float* wbase = wr + l * NS * D;
#pragma unroll
  for (int r = 0; r < 8; ++r) {
    int n = wave * 8 + r;
    const float* w = wbase + n * D;
    float p = 0.f;
#pragma unroll
    for (int jj = 0; jj < 4; ++jj) {
      int j = lane + jj * 64;
      p = fmaf(w[j], sx[j], p);
    }
    p = wave_reduce_sum(p);
    if (lane == 0) slog[n] = p;
  }
  if (wave == 0) {
    float p = sx[lane] + sx[lane + 64] + sx[lane + 128] + sx[lane + 192];
    p = wave_reduce_sum(p);
    if (lane == 0) s_aw = p * (1.f / D);
  }
  __syncthreads();
  if (wave == 0) {
    float aw = s_aw;
    float v = (lane < NS) ? slog[lane] : -INFINITY;
    float m = wave_reduce_max(v);
    float e = (lane < NS) ? __expf(v - m) : 0.f;
    float s = wave_reduce_sum(e);
    if (lane < NS) wlsT[(l * NS + lane) * B + b] = (e / s) * aw;
    if (lane == 0) a_words[bl] = aw;
  }
}

// ---------------------------------------------------------------------------
// K2: weighted_c[b,s] = sum_l wlsT[l][s][b]; a_slots = wc / sum_l a_words.
// ---------------------------------------------------------------------------
__global__ __launch_bounds__(64) void k2_slots_agg(
    const float* __restrict__ wlsT, const float* __restrict__ a_words,
    float* __restrict__ weighted_c, float* __restrict__ a_slots) {
  int b = blockIdx.x;
  int lane = threadIdx.x;
  float aw = a_words[b * L + lane];
  float sa = wave_reduce_sum(aw);
  if (lane < NS) {
    float wc = 0.f;
    for (int l = 0; l < L; ++l) wc += wlsT[(l * NS + lane) * B + b];
    weighted_c[b * NS + lane] = wc;
    a_slots[b * NS + lane] = wc / sa;
  }
}

// ---------------------------------------------------------------------------
// FUSED k3+k6.  k6 role: w_pose_si column-sum (pure HBM streaming).
// k3 role: split-bf16 MFMA GEMM.  A (scaled tf) double-buffered in 64KB
// swizzled LDS (single lgkm-barrier/step); W per-lane global->reg, prefetch
// depth 2; A reg-prefetch depth 1.  Wave grid 2x2: wave owns 64b x 32i ->
// A-LDS reads halved vs 1x4; wm-pair's duplicate W loads hit L2.
// 3-term emulated fp32: Ah*Bh + Ah*Bl + Al*Bh.
// ---------------------------------------------------------------------------
#define ATILE 8192  // 128*64 ushorts = 16KB per buffer

__global__ __launch_bounds__(256, 2) void k3k6(
    const float* __restrict__ tf, const float* __restrict__ wp,
    const float* __restrict__ wlsT, const float* __restrict__ wps,
    float* __restrict__ part, float* __restrict__ wsum,
    int nsplit, int nk3) {
  union Smem {
    struct { ushort Ah[2 * ATILE], Al[2 * ATILE]; } k3;  // 64KB
    struct { float red[4][D]; } k6;
  };
  __shared__ Smem sm;

  int bx = blockIdx.x;
  int t  = threadIdx.x;

  bool isK6;
  int idx;
  if (nk3 == 512) {  // 1:1 interleave (k6 streams while k3 is LDS/MFMA-busy)
    isK6 = (bx & 1);
    idx  = bx >> 1;
  } else {
    isK6 = bx < NS * NI;
    idx  = isK6 ? bx : bx - NS * NI;
  }

  if (isK6) {
    int si = idx;
    int k4 = (t & 63) * 4;
    int jg = t >> 6;
    const float* base = wps + (size_t)si * D * D;
    float4 acc = {0.f, 0.f, 0.f, 0.f};
    for (int j = jg; j < D; j += 4) {
      float4 v = *(const float4*)(base + (size_t)j * D + k4);
      acc.x += v.x; acc.y += v.y; acc.z += v.z; acc.w += v.w;
    }
    *(float4*)&sm.k6.red[jg][k4] = acc;
    __syncthreads();
    wsum[si * D + t] = (sm.k6.red[0][t] + sm.k6.red[1][t]) +
                       (sm.k6.red[2][t] + sm.k6.red[3][t]);
    return;
  }

  // ---- k3 path ----
  int sp  = idx % nsplit;
  int rem = idx / nsplit;
  int it  = rem & 3;
  int s   = rem >> 2;
  int i0  = it * 64;
  int lchunk = L / nsplit;
  int l0     = sp * lchunk;
  int steps  = lchunk * 4;  // 4 jc-chunks of 64 per l (even)

  int lane = t & 63, wv = t >> 6;
  int wm = wv >> 1, wn = wv & 1;       // 2x2 wave grid
  int fr = lane & 15, q = lane >> 4;
  int rw = t >> 4, jq = (t & 15) * 4;  // A-staging: row 0..15, col-quad

  f32x4 acc[4][2];
#pragma unroll
  for (int mi = 0; mi < 4; ++mi)
#pragma unroll
    for (int ni = 0; ni < 2; ++ni) acc[mi][ni] = (f32x4)0.f;

  float4 rA[8];
  float  rS[8];
  float4 rWa[8], rWb[8];

  auto loadA = [&](int step) {
    if (step >= steps) step = steps - 1;
    int l = l0 + (step >> 2), jc = (step & 3) * 64;
    const float* ab = tf + (size_t)l * D + jc + jq;
    const float* sb = wlsT + ((size_t)l * NS + s) * B;
#pragma unroll
    for (int p = 0; p < 8; ++p) {
      int bb = p * 16 + rw;
      rA[p] = *(const float4*)(ab + (size_t)bb * (L * D));
      rS[p] = sb[bb];
    }
  };
  auto loadW = [&](int step, float4 (&rW)[8]) {
    if (step >= steps) step = steps - 1;
    int l = l0 + (step >> 2), jc = (step & 3) * 64;
    const float* w0 = wp + ((size_t)l * NS + s) * (D * D) + jc + q * 8;
#pragma unroll
    for (int ni = 0; ni < 2; ++ni) {
      const float* wr_ = w0 + (size_t)(i0 + wn * 32 + ni * 16 + fr) * D;
#pragma unroll
      for (int k2 = 0; k2 < 2; ++k2) {
        rW[k2 * 4 + ni * 2 + 0] = *(const float4*)(wr_ + k2 * 32);
        rW[k2 * 4 + ni * 2 + 1] = *(const float4*)(wr_ + k2 * 32 + 4);
      }
    }
  };
  auto stageA = [&](int wofs) {  // consumes rA/rS (compiler vmcnt-waits)
#pragma unroll
    for (int p = 0; p < 8; ++p) {
      int bb = p * 16 + rw;
      float4 v = rA[p];
      float sc = rS[p];
      v.x *= sc; v.y *= sc; v.z *= sc; v.w *= sc;
      uint2 h, lo;
      split4(v, h, lo);
      int ix = swzA(bb, jq);
      *(uint2*)&sm.k3.Ah[wofs + ix] = h;
      *(uint2*)&sm.k3.Al[wofs + ix] = lo;
    }
  };
  auto mfmaStep = [&](const float4 (&rW)[8], int rofs) {
#pragma unroll
    for (int k2 = 0; k2 < 2; ++k2) {
      bf16x8 bh[2], bl[2];
#pragma unroll
      for (int ni = 0; ni < 2; ++ni) {
        uint2 h0, e0, h1, e1;
        split4(rW[k2 * 4 + ni * 2 + 0], h0, e0);
        split4(rW[k2 * 4 + ni * 2 + 1], h1, e1);
        uint4 hu = {h0.x, h0.y, h1.x, h1.y};
        uint4 lu = {e0.x, e0.y, e1.x, e1.y};
        bh[ni] = __builtin_bit_cast(bf16x8, hu);
        bl[ni] = __builtin_bit_cast(bf16x8, lu);
      }
      int kb = k2 * 32 + q * 8;
#pragma unroll
      for (int mi = 0; mi < 4; ++mi) {
        int ix = swzA(wm * 64 + mi * 16 + fr, kb);
        bf16x8 ah = *(const bf16x8*)&sm.k3.Ah[rofs + ix];
        bf16x8 al = *(const bf16x8*)&sm.k3.Al[rofs + ix];
#pragma unroll
        for (int ni = 0; ni < 2; ++ni) {
          acc[mi][ni] = __builtin_amdgcn_mfma_f32_16x16x32_bf16(ah, bh[ni], acc[mi][ni], 0, 0, 0);
          acc[mi][ni] = __builtin_amdgcn_mfma_f32_16x16x32_bf16(ah, bl[ni], acc[mi][ni], 0, 0, 0);
          acc[mi][ni] = __builtin_amdgcn_mfma_f32_16x16x32_bf16(al, bh[ni], acc[mi][ni], 0, 0, 0);
        }
      }
    }
  };

  // prologue: buf0 = A(0); W(0)->rWa, W(1)->rWb; A(1) in flight
  loadA(0);
  loadW(0, rWa);
  loadW(1, rWb);
  stageA(0);
  loadA(1);
  LGKM_BARRIER();

  for (int tt = 0; tt < steps; tt += 2) {
    // even step tt: compute buf0 with W(tt); stage A(tt+1)->buf1
    mfmaStep(rWa, 0);
    stageA(ATILE);
    loadA(tt + 2);
    loadW(tt + 2, rWa);
    LGKM_BARRIER();
    // odd step tt+1: compute buf1 with W(tt+1); stage A(tt+2)->buf0
    mfmaStep(rWb, ATILE);
    stageA(0);
    loadA(tt + 3);
    loadW(tt + 3, rWb);
    LGKM_BARRIER();
  }

  // epilogue: write partials
  float* pout = part + ((size_t)sp * NS + s) * (B * D);
#pragma unroll
  for (int mi = 0; mi < 4; ++mi)
#pragma unroll
    for (int ni = 0; ni < 2; ++ni) {
      int col = i0 + wn * 32 + ni * 16 + fr;
#pragma unroll
      for (int r = 0; r < 4; ++r) {
        int bb = wm * 64 + mi * 16 + q * 4 + r;
        pout[(size_t)bb * D + col] = acc[mi][ni][r];
      }
    }
}

// ---------------------------------------------------------------------------
// K3R: u_slots[b,s,i] = (sum_sp part[sp,s,b,i]) / weighted_c[b,s]
// ---------------------------------------------------------------------------
__global__ __launch_bounds__(256) void k3r_reduce(
    const float* __restrict__ part, const float* __restrict__ wc,
    float* __restrict__ u_slots, int nsplit) {
  int idx = blockIdx.x * 256 + threadIdx.x;  // over (s,b,i)
  int i  = idx & (D - 1);
  int sb = idx >> 8;
  int b  = sb & (B - 1);
  int s  = sb >> 7;
  float v = 0.f;
  for (int sp = 0; sp < nsplit; ++sp)
    v += part[(size_t)sp * (NS * B * D) + idx];
  u_slots[((size_t)b * NS + s) * D + i] = v / wc[b * NS + s];
}

// ---------------------------------------------------------------------------
// K4: per (b,s): logits2 = w_route_si[s] . u_slots[b,s]; softmax over NI;
//     w2 = c_si * a_slots.
// ---------------------------------------------------------------------------
__global__ __launch_bounds__(64) void k4_route_si(
    const float* __restrict__ u_slots, const float* __restrict__ wr_si,
    const float* __restrict__ a_slots, float* __restrict__ w2) {
  int bs = blockIdx.x;
  int s  = bs & (NS - 1);
  int lane = threadIdx.x;
  __shared__ float su[D];
  __shared__ float slog[NI];
#pragma unroll
  for (int jj = 0; jj < 4; ++jj) su[lane + jj * 64] = u_slots[bs * D + lane + jj * 64];
  __syncthreads();
  for (int i = 0; i < NI; ++i) {
    const float* w = wr_si + (s * NI + i) * D;
    float p = 0.f;
#pragma unroll
    for (int jj = 0; jj < 4; ++jj) {
      int j = lane + jj * 64;
      p = fmaf(w[j], su[j], p);
    }
    p = wave_reduce_sum(p);
    if (lane == 0) slog[i] = p;
  }
  __syncthreads();
  float v = (lane < NI) ? slog[lane] : -INFINITY;
  float m = wave_reduce_max(v);
  float e = (lane < NI) ? __expf(v - m) : 0.f;
  float ssum = wave_reduce_sum(e);
  if (lane < NI) w2[bs * NI + lane] = (e / ssum) * a_slots[bs];
}

// ---------------------------------------------------------------------------
// K5: wc2[b,i] = sum_s w2; a_intents = wc2 / sum_s a_slots.
// ---------------------------------------------------------------------------
__global__ __launch_bounds__(64) void k5_intents_agg(
    const float* __restrict__ w2, const float* __restrict__ a_slots,
    float* __restrict__ wc2, float* __restrict__ a_intents) {
  int b = blockIdx.x;
  int lane = threadIdx.x;
  float as = (lane < NS) ? a_slots[b * NS + lane] : 0.f;
  float sas = wave_reduce_sum(as);
  if (lane < NI) {
    float wc = 0.f;
    for (int s = 0; s < NS; ++s) wc += w2[(b * NS + s) * NI + lane];
    wc2[b * NI + lane] = wc;
    a_intents[b * NI + lane] = wc / sas;
  }
}

// ---------------------------------------------------------------------------
// K7: u_intents[b,i,k] = sum_s w2[b,s,i]*u_slots[b,s,k]*Wsum[s,i,k] / wc2[b,i]
// ---------------------------------------------------------------------------
__global__ __launch_bounds__(256) void k7_uintents(
    const float* __restrict__ u_slots, const float* __restrict__ w2,
    const float* __restrict__ wsum, const float* __restrict__ wc2,
    float* __restrict__ u_intents) {
  int bi = blockIdx.x;
  int b = bi >> 4, i = bi & (NI - 1);
  int k = threadIdx.x;
  float acc = 0.f;
  for (int s = 0; s < NS; ++s) {
    float w = w2[(b * NS + s) * NI + i];
    acc = fmaf(w * u_slots[(b * NS + s) * D + k], wsum[(s * NI + i) * D + k], acc);
  }
  u_intents[bi * D + k] = acc / wc2[bi];
}

// ---------------------------------------------------------------------------
extern "C" void kernel_launch(void* const* d_in, const int* in_sizes, int n_in,
                              void* d_out, int out_size, void* d_ws, size_t ws_size,
                              hipStream_t stream) {
  const float* tf    = (const float*)d_in[0];  // (B,L,D)
  const float* wr_ws = (const float*)d_in[1];  // (L,NS,D)
  const float* wp_ws = (const float*)d_in[2];  // (L,NS,D,D)
  const float* wr_si = (const float*)d_in[3];  // (NS,NI,D)
  const float* wp_si = (const float*)d_in[4];  // (NS,NI,D,D)

  float* out       = (float*)d_out;
  float* a_slots   = out;                      // B*NS
  float* u_slots   = a_slots + B * NS;         // B*NS*D
  float* a_intents = u_slots + B * NS * D;     // B*NI
  float* u_intents = a_intents + B * NI;       // B*NI*D

  float* ws         = (float*)d_ws;
  float* wlsT       = ws;                      // L*NS*B  = 262144
  float* a_words    = wlsT + L * NS * B;       // B*L     = 8192
  float* weighted_c = a_words + B * L;         // B*NS    = 4096
  float* w2         = weighted_c + B * NS;     // B*NS*NI = 65536
  float* wc2        = w2 + B * NS * NI;        // B*NI    = 2048
  float* wsum       = wc2 + B * NI;            // NS*NI*D = 131072
  float* part       = wsum + NS * NI * D;      // nsplit * NS*B*D

  const size_t base_f  = 473088;
  const size_t chunk_f = (size_t)NS * B * D;   // 1,048,576 floats per split
  size_t avail_f = ws_size / sizeof(float);
  int nsplit = 1;
  if (avail_f >= base_f + 4 * chunk_f)      nsplit = 4;
  else if (avail_f >= base_f + 2 * chunk_f) nsplit = 2;

  int nk3  = 128 * nsplit;  // 32 s x 4 i-tiles x nsplit
  int grid = nk3 + NS * NI;

  k1_route_words<<<B * L, 256, 0, stream>>>(tf, wr_ws, wlsT, a_words);
  k2_slots_agg<<<B, 64, 0, stream>>>(wlsT, a_words, weighted_c, a_slots);
  k3k6<<<grid, 256, 0, stream>>>(tf, wp_ws, wlsT, wp_si, part, wsum,
                                 nsplit, nk3);
  k3r_reduce<<<(NS * B * D) / 256, 256, 0, stream>>>(part, weighted_c, u_slots, nsplit);
  k4_route_si<<<B * NS, 64, 0, stream>>>(u_slots, wr_si, a_slots, w2);
  k5_intents_agg<<<B, 64, 0, stream>>>(w2, a_slots, wc2, a_intents);
  k7_uintents<<<B * NI, 256, 0, stream>>>(u_slots, w2, wsum, wc2, u_intents);
}

// Round 7
// 297.537 us; speedup vs baseline: 1.5610x; 1.5610x over previous
//
#include <hip/hip_runtime.h>
#include <math.h>

#define B  128
#define L  64
#define NS 32
#define NI 16
#define D  256

typedef __attribute__((ext_vector_type(8))) short bf16x8;
typedef __attribute__((ext_vector_type(4))) float f32x4;

__device__ __forceinline__ float wave_reduce_sum(float v) {
#pragma unroll
  for (int off = 32; off; off >>= 1) v += __shfl_xor(v, off, 64);
  return v;
}
__device__ __forceinline__ float wave_reduce_max(float v) {
#pragma unroll
  for (int off = 32; off; off >>= 1) v = fmaxf(v, __shfl_xor(v, off, 64));
  return v;
}

// packed RTNE f32x2 -> bf16x2 (single HW instr)
__device__ __forceinline__ uint cvt_pk_bf16(float a, float b) {
  uint r;
  asm("v_cvt_pk_bf16_f32 %0, %1, %2" : "=v"(r) : "v"(a), "v"(b));
  return r;  // lo16 = bf16(a), hi16 = bf16(b)
}
// float4 -> hi-pair u32x2 + lo-pair u32x2 (x ~= hi + lo, residual ~2^-17)
__device__ __forceinline__ void split4(float4 v, uint2& h, uint2& lo) {
  h.x = cvt_pk_bf16(v.x, v.y);
  h.y = cvt_pk_bf16(v.z, v.w);
  float h0 = __uint_as_float(h.x << 16);
  float h1 = __uint_as_float(h.x & 0xFFFF0000u);
  float h2 = __uint_as_float(h.y << 16);
  float h3 = __uint_as_float(h.y & 0xFFFF0000u);
  lo.x = cvt_pk_bf16(v.x - h0, v.y - h1);
  lo.y = cvt_pk_bf16(v.z - h2, v.w - h3);
}

// async global->LDS DMA, 16B per lane (wave-uniform LDS base + lane*16)
__device__ __forceinline__ void dma16(const void* g, void* l) {
  __builtin_amdgcn_global_load_lds(
      (const __attribute__((address_space(1))) void*)g,
      (__attribute__((address_space(3))) void*)l, 16, 0, 0);
}

// swizzled ushort index into a [128 rows][64 k] bf16 tile (128B rows).
// XOR (row&7)<<4 into the byte offset -> b128 reads bank-spread.  The SAME
// function generates the precomputed global image, so a LINEAR DMA copy
// lands correctly swizzled (pre-swizzled-source pattern).
__device__ __forceinline__ int swzA(int row, int kcol) {
  int byte = (row << 7) + (kcol << 1);
  byte ^= (row & 7) << 4;
  return byte >> 1;
}

// ---------------------------------------------------------------------------
// KX: precompute swizzled bf16 hi/lo images of tf.
// Tile (l, jci): [128 b][64 k] where k = jci*64 + 0..63.  16KB per image tile.
// ---------------------------------------------------------------------------
__global__ __launch_bounds__(256) void kx_split(
    const float* __restrict__ tf, ushort* __restrict__ xh,
    ushort* __restrict__ xl) {
  int tile = blockIdx.x;          // l*4 + jci
  int l  = tile >> 2;
  int jc = (tile & 3) * 64;
  int t  = threadIdx.x;
  int row = t >> 1;               // b
  int k0  = (t & 1) * 32;
  const float* src = tf + ((size_t)row * L + l) * D + jc + k0;
  ushort* ht = xh + (size_t)tile * 8192;
  ushort* lt = xl + (size_t)tile * 8192;
#pragma unroll
  for (int c = 0; c < 8; ++c) {
    float4 v = *(const float4*)(src + c * 4);
    uint2 h, lo;
    split4(v, h, lo);
    int ix = swzA(row, k0 + c * 4);
    *(uint2*)&ht[ix] = h;
    *(uint2*)&lt[ix] = lo;
  }
}

// ---------------------------------------------------------------------------
// K1: per (b,l): a_words = mean(x); logits = w_route_ws[l] . x; softmax;
//     wlsT[l][s][b] = c_ws * a_words.
// ---------------------------------------------------------------------------
__global__ __launch_bounds__(256) void k1_route_words(
    const float* __restrict__ tf, const float* __restrict__ wr,
    float* __restrict__ wlsT, float* __restrict__ a_words) {
  int bl = blockIdx.x;
  int b  = bl >> 6;
  int l  = bl & (L - 1);
  int t  = threadIdx.x;
  int wave = t >> 6, lane = t & 63;
  __shared__ float sx[D];
  __shared__ float slog[NS];
  __shared__ float s_aw;
  sx[t] = tf[bl * D + t];
  __syncthreads();
  const float* wbase = wr + l * NS * D;
#pragma unroll
  for (int r = 0; r < 8; ++r) {
    int n = wave * 8 + r;
    const float* w = wbase + n * D;
    float p = 0.f;
#pragma unroll
    for (int jj = 0; jj < 4; ++jj) {
      int j = lane + jj * 64;
      p = fmaf(w[j], sx[j], p);
    }
    p = wave_reduce_sum(p);
    if (lane == 0) slog[n] = p;
  }
  if (wave == 0) {
    float p = sx[lane] + sx[lane + 64] + sx[lane + 128] + sx[lane + 192];
    p = wave_reduce_sum(p);
    if (lane == 0) s_aw = p * (1.f / D);
  }
  __syncthreads();
  if (wave == 0) {
    float aw = s_aw;
    float v = (lane < NS) ? slog[lane] : -INFINITY;
    float m = wave_reduce_max(v);
    float e = (lane < NS) ? __expf(v - m) : 0.f;
    float s = wave_reduce_sum(e);
    if (lane < NS) wlsT[(l * NS + lane) * B + b] = (e / s) * aw;
    if (lane == 0) a_words[bl] = aw;
  }
}

// ---------------------------------------------------------------------------
// K2: weighted_c[b,s] = sum_l wlsT[l][s][b]; a_slots = wc / sum_l a_words.
// ---------------------------------------------------------------------------
__global__ __launch_bounds__(64) void k2_slots_agg(
    const float* __restrict__ wlsT, const float* __restrict__ a_words,
    float* __restrict__ weighted_c, float* __restrict__ a_slots) {
  int b = blockIdx.x;
  int lane = threadIdx.x;
  float aw = a_words[b * L + lane];
  float sa = wave_reduce_sum(aw);
  if (lane < NS) {
    float wc = 0.f;
    for (int l = 0; l < L; ++l) wc += wlsT[(l * NS + lane) * B + b];
    weighted_c[b * NS + lane] = wc;
    a_slots[b * NS + lane] = wc / sa;
  }
}

// ---------------------------------------------------------------------------
// K3 v4 (m97 structure): per block (s, i-tile 64, l-chunk):
//   R[b,i] = sum_l wls[b,l,s] * (sum_j W[l,s,i,j] * x[b,l,j])
// A = pre-split swizzled bf16 images, staged via global_load_lds DMA (no
// VALU, no VGPR round-trip).  W = per-lane global f32 -> split in regs.
// Scale applied per-l in fp32 epilogue (R += sw[b]*P), so the split is
// scale-independent.  Simple 2-barrier loop; overlap via 2 blocks/CU.
// 2x2 wave grid: wave = 64 b-rows x 32 i-cols; 48 MFMA/step/wave.
// ---------------------------------------------------------------------------
__global__ __launch_bounds__(256) void k3_mfma(
    const ushort* __restrict__ xh, const ushort* __restrict__ xl,
    const float* __restrict__ wp, const float* __restrict__ wlsT,
    float* __restrict__ part, int nsplit) {
  __shared__ ushort Ah[8192], Al[8192];  // 16KB + 16KB
  __shared__ float sw[128];

  int bx  = blockIdx.x;
  int sp  = bx % nsplit;
  int rem = bx / nsplit;
  int it  = rem & 3;
  int s   = rem >> 2;
  int i0  = it * 64;
  int lchunk = L / nsplit;
  int l0     = sp * lchunk;
  int steps  = lchunk * 4;

  int t = threadIdx.x;
  int lane = t & 63, wv = t >> 6;
  int wm = wv >> 1, wn = wv & 1;
  int fr = lane & 15, q = lane >> 4;

  f32x4 P[4][2], R[4][2];
#pragma unroll
  for (int mi = 0; mi < 4; ++mi)
#pragma unroll
    for (int ni = 0; ni < 2; ++ni) { P[mi][ni] = (f32x4)0.f; R[mi][ni] = (f32x4)0.f; }

  for (int step = 0; step < steps; ++step) {
    int l   = l0 + (step >> 2);
    int jci = step & 3;
    // ---- [A] issue A-tile DMA (32KB, pre-swizzled source -> linear LDS) ----
    size_t tile = ((size_t)l * 4 + jci) * 8192;
    const ushort* th = xh + tile;
    const ushort* tl = xl + tile;
#pragma unroll
    for (int ii = 0; ii < 4; ++ii) {
      int ofs = (wv * 4 + ii) * 512;  // 1KB chunks (ushort idx)
      dma16(th + ofs + lane * 8, &Ah[ofs]);
      dma16(tl + ofs + lane * 8, &Al[ofs]);
    }
    // ---- issue W loads (f32, per-lane fragment rows) ----
    int jc = jci * 64;
    float4 rW[8];
    const float* wb = wp + ((size_t)l * NS + s) * (D * D) + jc + q * 8;
#pragma unroll
    for (int ni = 0; ni < 2; ++ni) {
      const float* wr_ = wb + (size_t)(i0 + wn * 32 + ni * 16 + fr) * D;
#pragma unroll
      for (int k2 = 0; k2 < 2; ++k2) {
        rW[(ni * 2 + k2) * 2 + 0] = *(const float4*)(wr_ + k2 * 32);
        rW[(ni * 2 + k2) * 2 + 1] = *(const float4*)(wr_ + k2 * 32 + 4);
      }
    }
    // ---- wls scales for this l (first jc-step of the l) ----
    if (jci == 0 && t < 128) sw[t] = wlsT[((size_t)l * NS + s) * B + t];
    __syncthreads();  // drains DMA (vmcnt 0) + W loads + sw store

    // ---- [B] split W in regs ----
    bf16x8 bh[2][2], bl[2][2];  // [ni][k2]
#pragma unroll
    for (int ni = 0; ni < 2; ++ni)
#pragma unroll
      for (int k2 = 0; k2 < 2; ++k2) {
        uint2 h0, e0, h1, e1;
        split4(rW[(ni * 2 + k2) * 2 + 0], h0, e0);
        split4(rW[(ni * 2 + k2) * 2 + 1], h1, e1);
        uint4 hu = {h0.x, h0.y, h1.x, h1.y};
        uint4 lu = {e0.x, e0.y, e1.x, e1.y};
        bh[ni][k2] = __builtin_bit_cast(bf16x8, hu);
        bl[ni][k2] = __builtin_bit_cast(bf16x8, lu);
      }
    // ---- MFMA: 3-term emulated fp32 into per-l accumulator P ----
#pragma unroll
    for (int k2 = 0; k2 < 2; ++k2) {
      int kb = k2 * 32 + q * 8;
#pragma unroll
      for (int mi = 0; mi < 4; ++mi) {
        int ix = swzA(wm * 64 + mi * 16 + fr, kb);
        bf16x8 ah = *(const bf16x8*)&Ah[ix];
        bf16x8 al = *(const bf16x8*)&Al[ix];
#pragma unroll
        for (int ni = 0; ni < 2; ++ni) {
          P[mi][ni] = __builtin_amdgcn_mfma_f32_16x16x32_bf16(ah, bh[ni][k2], P[mi][ni], 0, 0, 0);
          P[mi][ni] = __builtin_amdgcn_mfma_f32_16x16x32_bf16(ah, bl[ni][k2], P[mi][ni], 0, 0, 0);
          P[mi][ni] = __builtin_amdgcn_mfma_f32_16x16x32_bf16(al, bh[ni][k2], P[mi][ni], 0, 0, 0);
        }
      }
    }
    // ---- per-l scale epilogue: R += sw[b] * P (fp32) ----
    if (jci == 3) {
#pragma unroll
      for (int mi = 0; mi < 4; ++mi) {
        f32x4 s4 = *(const f32x4*)&sw[wm * 64 + mi * 16 + q * 4];
#pragma unroll
        for (int ni = 0; ni < 2; ++ni) {
          R[mi][ni] += s4 * P[mi][ni];
          P[mi][ni] = (f32x4)0.f;
        }
      }
    }
    __syncthreads();  // readers done before next DMA overwrites
  }

  // ---- epilogue: write partials ----
  float* pout = part + ((size_t)sp * NS + s) * (B * D);
#pragma unroll
  for (int mi = 0; mi < 4; ++mi)
#pragma unroll
    for (int ni = 0; ni < 2; ++ni) {
      int col = i0 + wn * 32 + ni * 16 + fr;
#pragma unroll
      for (int r = 0; r < 4; ++r) {
        int bb = wm * 64 + mi * 16 + q * 4 + r;
        pout[(size_t)bb * D + col] = R[mi][ni][r];
      }
    }
}

// ---------------------------------------------------------------------------
// K3R: u_slots[b,s,i] = (sum_sp part[sp,s,b,i]) / weighted_c[b,s]
// ---------------------------------------------------------------------------
__global__ __launch_bounds__(256) void k3r_reduce(
    const float* __restrict__ part, const float* __restrict__ wc,
    float* __restrict__ u_slots, int nsplit) {
  int idx = blockIdx.x * 256 + threadIdx.x;  // over (s,b,i)
  int i  = idx & (D - 1);
  int sb = idx >> 8;
  int b  = sb & (B - 1);
  int s  = sb >> 7;
  float v = 0.f;
  for (int sp = 0; sp < nsplit; ++sp)
    v += part[(size_t)sp * (NS * B * D) + idx];
  u_slots[((size_t)b * NS + s) * D + i] = v / wc[b * NS + s];
}

// ---------------------------------------------------------------------------
// K4: per (b,s): logits2 = w_route_si[s] . u_slots[b,s]; softmax over NI;
//     w2 = c_si * a_slots.
// ---------------------------------------------------------------------------
__global__ __launch_bounds__(64) void k4_route_si(
    const float* __restrict__ u_slots, const float* __restrict__ wr_si,
    const float* __restrict__ a_slots, float* __restrict__ w2) {
  int bs = blockIdx.x;
  int s  = bs & (NS - 1);
  int lane = threadIdx.x;
  __shared__ float su[D];
  __shared__ float slog[NI];
#pragma unroll
  for (int jj = 0; jj < 4; ++jj) su[lane + jj * 64] = u_slots[bs * D + lane + jj * 64];
  __syncthreads();
  for (int i = 0; i < NI; ++i) {
    const float* w = wr_si + (s * NI + i) * D;
    float p = 0.f;
#pragma unroll
    for (int jj = 0; jj < 4; ++jj) {
      int j = lane + jj * 64;
      p = fmaf(w[j], su[j], p);
    }
    p = wave_reduce_sum(p);
    if (lane == 0) slog[i] = p;
  }
  __syncthreads();
  float v = (lane < NI) ? slog[lane] : -INFINITY;
  float m = wave_reduce_max(v);
  float e = (lane < NI) ? __expf(v - m) : 0.f;
  float ssum = wave_reduce_sum(e);
  if (lane < NI) w2[bs * NI + lane] = (e / ssum) * a_slots[bs];
}

// ---------------------------------------------------------------------------
// K5: wc2[b,i] = sum_s w2; a_intents = wc2 / sum_s a_slots.
// ---------------------------------------------------------------------------
__global__ __launch_bounds__(64) void k5_intents_agg(
    const float* __restrict__ w2, const float* __restrict__ a_slots,
    float* __restrict__ wc2, float* __restrict__ a_intents) {
  int b = blockIdx.x;
  int lane = threadIdx.x;
  float as = (lane < NS) ? a_slots[b * NS + lane] : 0.f;
  float sas = wave_reduce_sum(as);
  if (lane < NI) {
    float wc = 0.f;
    for (int s = 0; s < NS; ++s) wc += w2[(b * NS + s) * NI + lane];
    wc2[b * NI + lane] = wc;
    a_intents[b * NI + lane] = wc / sas;
  }
}

// ---------------------------------------------------------------------------
// K6: Wsum[s,i,k] = sum_j w_pose_si[s,i,j,k] (float4-vectorized over k).
// ---------------------------------------------------------------------------
__global__ __launch_bounds__(256) void k6_wsum(
    const float* __restrict__ wps, float* __restrict__ wsum) {
  __shared__ float red[4][D];
  int si = blockIdx.x;
  int t  = threadIdx.x;
  int k4 = (t & 63) * 4;
  int jg = t >> 6;
  const float* base = wps + (size_t)si * D * D;
  float4 acc = {0.f, 0.f, 0.f, 0.f};
  for (int j = jg; j < D; j += 4) {
    float4 v = *(const float4*)(base + (size_t)j * D + k4);
    acc.x += v.x; acc.y += v.y; acc.z += v.z; acc.w += v.w;
  }
  *(float4*)&red[jg][k4] = acc;
  __syncthreads();
  wsum[si * D + t] = (red[0][t] + red[1][t]) + (red[2][t] + red[3][t]);
}

// ---------------------------------------------------------------------------
// K7: u_intents[b,i,k] = sum_s w2[b,s,i]*u_slots[b,s,k]*Wsum[s,i,k] / wc2[b,i]
// ---------------------------------------------------------------------------
__global__ __launch_bounds__(256) void k7_uintents(
    const float* __restrict__ u_slots, const float* __restrict__ w2,
    const float* __restrict__ wsum, const float* __restrict__ wc2,
    float* __restrict__ u_intents) {
  int bi = blockIdx.x;
  int b = bi >> 4, i = bi & (NI - 1);
  int k = threadIdx.x;
  float acc = 0.f;
  for (int s = 0; s < NS; ++s) {
    float w = w2[(b * NS + s) * NI + i];
    acc = fmaf(w * u_slots[(b * NS + s) * D + k], wsum[(s * NI + i) * D + k], acc);
  }
  u_intents[bi * D + k] = acc / wc2[bi];
}

// ---------------------------------------------------------------------------
extern "C" void kernel_launch(void* const* d_in, const int* in_sizes, int n_in,
                              void* d_out, int out_size, void* d_ws, size_t ws_size,
                              hipStream_t stream) {
  const float* tf    = (const float*)d_in[0];  // (B,L,D)
  const float* wr_ws = (const float*)d_in[1];  // (L,NS,D)
  const float* wp_ws = (const float*)d_in[2];  // (L,NS,D,D)
  const float* wr_si = (const float*)d_in[3];  // (NS,NI,D)
  const float* wp_si = (const float*)d_in[4];  // (NS,NI,D,D)

  float* out       = (float*)d_out;
  float* a_slots   = out;                      // B*NS
  float* u_slots   = a_slots + B * NS;         // B*NS*D
  float* a_intents = u_slots + B * NS * D;     // B*NI
  float* u_intents = a_intents + B * NI;       // B*NI*D

  float* ws         = (float*)d_ws;
  float* wlsT       = ws;                      // L*NS*B  = 262144
  float* a_words    = wlsT + L * NS * B;       // B*L     = 8192
  float* weighted_c = a_words + B * L;         // B*NS    = 4096
  float* w2         = weighted_c + B * NS;     // B*NS*NI = 65536
  float* wc2        = w2 + B * NS * NI;        // B*NI    = 2048
  float* wsum       = wc2 + B * NI;            // NS*NI*D = 131072
  // bf16 hi/lo swizzled images of tf: 64*4 tiles x 8192 ushorts each
  ushort* xh        = (ushort*)(wsum + NS * NI * D);    // 2,097,152 ushorts
  ushort* xl        = xh + (size_t)L * 4 * 8192;        // 2,097,152 ushorts
  float*  part      = (float*)(xl + (size_t)L * 4 * 8192);  // nsplit*NS*B*D

  const size_t base_f  = 473088 + 1048576 * 2 / 2 * 2;  // pre-part floats (incl. images)
  const size_t chunk_f = (size_t)NS * B * D;             // 1,048,576 per split
  size_t avail_f = ws_size / sizeof(float);
  int nsplit = 1;
  if (avail_f >= base_f + 4 * chunk_f)      nsplit = 4;
  else if (avail_f >= base_f + 2 * chunk_f) nsplit = 2;

  kx_split<<<L * 4, 256, 0, stream>>>(tf, xh, xl);
  k1_route_words<<<B * L, 256, 0, stream>>>(tf, wr_ws, wlsT, a_words);
  k2_slots_agg<<<B, 64, 0, stream>>>(wlsT, a_words, weighted_c, a_slots);
  k3_mfma<<<NS * 4 * nsplit, 256, 0, stream>>>(xh, xl, wp_ws, wlsT, part, nsplit);
  k3r_reduce<<<(NS * B * D) / 256, 256, 0, stream>>>(part, weighted_c, u_slots, nsplit);
  k6_wsum<<<NS * NI, 256, 0, stream>>>(wp_si, wsum);
  k4_route_si<<<B * NS, 64, 0, stream>>>(u_slots, wr_si, a_slots, w2);
  k5_intents_agg<<<B, 64, 0, stream>>>(w2, a_slots, wc2, a_intents);
  k7_uintents<<<B * NI, 256, 0, stream>>>(u_slots, w2, wsum, wc2, u_intents);
}

// Round 8
// 296.370 us; speedup vs baseline: 1.5671x; 1.0039x over previous
//
#include <hip/hip_runtime.h>
#include <math.h>

#define B  128
#define L  64
#define NS 32
#define NI 16
#define D  256

typedef __attribute__((ext_vector_type(8))) short bf16x8;
typedef __attribute__((ext_vector_type(4))) float f32x4;

__device__ __forceinline__ float wave_reduce_sum(float v) {
#pragma unroll
  for (int off = 32; off; off >>= 1) v += __shfl_xor(v, off, 64);
  return v;
}
__device__ __forceinline__ float wave_reduce_max(float v) {
#pragma unroll
  for (int off = 32; off; off >>= 1) v = fmaxf(v, __shfl_xor(v, off, 64));
  return v;
}

// packed RTNE f32x2 -> bf16x2 (single HW instr)
__device__ __forceinline__ uint cvt_pk_bf16(float a, float b) {
  uint r;
  asm("v_cvt_pk_bf16_f32 %0, %1, %2" : "=v"(r) : "v"(a), "v"(b));
  return r;  // lo16 = bf16(a), hi16 = bf16(b)
}
// float4 -> hi-pair u32x2 + lo-pair u32x2 (x ~= hi + lo, residual ~2^-17)
__device__ __forceinline__ void split4(float4 v, uint2& h, uint2& lo) {
  h.x = cvt_pk_bf16(v.x, v.y);
  h.y = cvt_pk_bf16(v.z, v.w);
  float h0 = __uint_as_float(h.x << 16);
  float h1 = __uint_as_float(h.x & 0xFFFF0000u);
  float h2 = __uint_as_float(h.y << 16);
  float h3 = __uint_as_float(h.y & 0xFFFF0000u);
  lo.x = cvt_pk_bf16(v.x - h0, v.y - h1);
  lo.y = cvt_pk_bf16(v.z - h2, v.w - h3);
}

// async global->LDS DMA, 16B per lane (wave-uniform LDS base + lane*16)
__device__ __forceinline__ void dma16(const void* g, void* l) {
  __builtin_amdgcn_global_load_lds(
      (const __attribute__((address_space(1))) void*)g,
      (__attribute__((address_space(3))) void*)l, 16, 0, 0);
}

// swizzled ushort index into a [128 rows][64 k] bf16 tile (128B rows).
// XOR (row&7)<<4 into the byte offset -> b128 reads bank-spread.  The SAME
// function generates the precomputed global image, so a LINEAR DMA copy
// lands correctly swizzled (pre-swizzled-source pattern).
__device__ __forceinline__ int swzA(int row, int kcol) {
  int byte = (row << 7) + (kcol << 1);
  byte ^= (row & 7) << 4;
  return byte >> 1;
}

// ---------------------------------------------------------------------------
// KX: precompute swizzled bf16 hi/lo images of tf.
// Tile (l, jci): [128 b][64 k] where k = jci*64 + 0..63.  16KB per image tile.
// ---------------------------------------------------------------------------
__global__ __launch_bounds__(256) void kx_split(
    const float* __restrict__ tf, ushort* __restrict__ xh,
    ushort* __restrict__ xl) {
  int tile = blockIdx.x;          // l*4 + jci
  int l  = tile >> 2;
  int jc = (tile & 3) * 64;
  int t  = threadIdx.x;
  int row = t >> 1;               // b
  int k0  = (t & 1) * 32;
  const float* src = tf + ((size_t)row * L + l) * D + jc + k0;
  ushort* ht = xh + (size_t)tile * 8192;
  ushort* lt = xl + (size_t)tile * 8192;
#pragma unroll
  for (int c = 0; c < 8; ++c) {
    float4 v = *(const float4*)(src + c * 4);
    uint2 h, lo;
    split4(v, h, lo);
    int ix = swzA(row, k0 + c * 4);
    *(uint2*)&ht[ix] = h;
    *(uint2*)&lt[ix] = lo;
  }
}

// ---------------------------------------------------------------------------
// K1: per (b,l): a_words = mean(x); logits = w_route_ws[l] . x; softmax;
//     wlsT[l][s][b] = c_ws * a_words.
// ---------------------------------------------------------------------------
__global__ __launch_bounds__(256) void k1_route_words(
    const float* __restrict__ tf, const float* __restrict__ wr,
    float* __restrict__ wlsT, float* __restrict__ a_words) {
  int bl = blockIdx.x;
  int b  = bl >> 6;
  int l  = bl & (L - 1);
  int t  = threadIdx.x;
  int wave = t >> 6, lane = t & 63;
  __shared__ float sx[D];
  __shared__ float slog[NS];
  __shared__ float s_aw;
  sx[t] = tf[bl * D + t];
  __syncthreads();
  const float* wbase = wr + l * NS * D;
#pragma unroll
  for (int r = 0; r < 8; ++r) {
    int n = wave * 8 + r;
    const float* w = wbase + n * D;
    float p = 0.f;
#pragma unroll
    for (int jj = 0; jj < 4; ++jj) {
      int j = lane + jj * 64;
      p = fmaf(w[j], sx[j], p);
    }
    p = wave_reduce_sum(p);
    if (lane == 0) slog[n] = p;
  }
  if (wave == 0) {
    float p = sx[lane] + sx[lane + 64] + sx[lane + 128] + sx[lane + 192];
    p = wave_reduce_sum(p);
    if (lane == 0) s_aw = p * (1.f / D);
  }
  __syncthreads();
  if (wave == 0) {
    float aw = s_aw;
    float v = (lane < NS) ? slog[lane] : -INFINITY;
    float m = wave_reduce_max(v);
    float e = (lane < NS) ? __expf(v - m) : 0.f;
    float s = wave_reduce_sum(e);
    if (lane < NS) wlsT[(l * NS + lane) * B + b] = (e / s) * aw;
    if (lane == 0) a_words[bl] = aw;
  }
}

// ---------------------------------------------------------------------------
// K2: weighted_c[b,s] = sum_l wlsT[l][s][b]; a_slots = wc / sum_l a_words.
// ---------------------------------------------------------------------------
__global__ __launch_bounds__(64) void k2_slots_agg(
    const float* __restrict__ wlsT, const float* __restrict__ a_words,
    float* __restrict__ weighted_c, float* __restrict__ a_slots) {
  int b = blockIdx.x;
  int lane = threadIdx.x;
  float aw = a_words[b * L + lane];
  float sa = wave_reduce_sum(aw);
  if (lane < NS) {
    float wc = 0.f;
    for (int l = 0; l < L; ++l) wc += wlsT[(l * NS + lane) * B + b];
    weighted_c[b * NS + lane] = wc;
    a_slots[b * NS + lane] = wc / sa;
  }
}

// ---------------------------------------------------------------------------
// K3 v4 (m97 structure): per block (s, i-tile 64, l-chunk):
//   R[b,i] = sum_l wls[b,l,s] * (sum_j W[l,s,i,j] * x[b,l,j])
// A = pre-split swizzled bf16 images, staged via global_load_lds DMA (no
// VALU, no VGPR round-trip).  W = per-lane global f32 -> split in regs.
// Scale applied per-l in fp32 epilogue (R += sw[b]*P), so the split is
// scale-independent.  Simple 2-barrier loop; overlap via 2 blocks/CU.
// 2x2 wave grid: wave = 64 b-rows x 32 i-cols; 48 MFMA/step/wave.
// ---------------------------------------------------------------------------
__global__ __launch_bounds__(256) void k3_mfma(
    const ushort* __restrict__ xh, const ushort* __restrict__ xl,
    const float* __restrict__ wp, const float* __restrict__ wlsT,
    float* __restrict__ part, int nsplit) {
  __shared__ ushort Ah[8192], Al[8192];  // 16KB + 16KB
  __shared__ float sw[128];

  int bx  = blockIdx.x;
  int sp  = bx % nsplit;
  int rem = bx / nsplit;
  int it  = rem & 3;
  int s   = rem >> 2;
  int i0  = it * 64;
  int lchunk = L / nsplit;
  int l0     = sp * lchunk;
  int steps  = lchunk * 4;

  int t = threadIdx.x;
  int lane = t & 63, wv = t >> 6;
  int wm = wv >> 1, wn = wv & 1;
  int fr = lane & 15, q = lane >> 4;

  f32x4 P[4][2], R[4][2];
#pragma unroll
  for (int mi = 0; mi < 4; ++mi)
#pragma unroll
    for (int ni = 0; ni < 2; ++ni) { P[mi][ni] = (f32x4)0.f; R[mi][ni] = (f32x4)0.f; }

  for (int step = 0; step < steps; ++step) {
    int l   = l0 + (step >> 2);
    int jci = step & 3;
    // ---- [A] issue A-tile DMA (32KB, pre-swizzled source -> linear LDS) ----
    size_t tile = ((size_t)l * 4 + jci) * 8192;
    const ushort* th = xh + tile;
    const ushort* tl = xl + tile;
#pragma unroll
    for (int ii = 0; ii < 4; ++ii) {
      int ofs = (wv * 4 + ii) * 512;  // 1KB chunks (ushort idx)
      dma16(th + ofs + lane * 8, &Ah[ofs]);
      dma16(tl + ofs + lane * 8, &Al[ofs]);
    }
    // ---- issue W loads (f32, per-lane fragment rows) ----
    int jc = jci * 64;
    float4 rW[8];
    const float* wb = wp + ((size_t)l * NS + s) * (D * D) + jc + q * 8;
#pragma unroll
    for (int ni = 0; ni < 2; ++ni) {
      const float* wr_ = wb + (size_t)(i0 + wn * 32 + ni * 16 + fr) * D;
#pragma unroll
      for (int k2 = 0; k2 < 2; ++k2) {
        rW[(ni * 2 + k2) * 2 + 0] = *(const float4*)(wr_ + k2 * 32);
        rW[(ni * 2 + k2) * 2 + 1] = *(const float4*)(wr_ + k2 * 32 + 4);
      }
    }
    // ---- wls scales for this l (first jc-step of the l) ----
    if (jci == 0 && t < 128) sw[t] = wlsT[((size_t)l * NS + s) * B + t];
    __syncthreads();  // drains DMA (vmcnt 0) + W loads + sw store

    // ---- [B] split W in regs ----
    bf16x8 bh[2][2], bl[2][2];  // [ni][k2]
#pragma unroll
    for (int ni = 0; ni < 2; ++ni)
#pragma unroll
      for (int k2 = 0; k2 < 2; ++k2) {
        uint2 h0, e0, h1, e1;
        split4(rW[(ni * 2 + k2) * 2 + 0], h0, e0);
        split4(rW[(ni * 2 + k2) * 2 + 1], h1, e1);
        uint4 hu = {h0.x, h0.y, h1.x, h1.y};
        uint4 lu = {e0.x, e0.y, e1.x, e1.y};
        bh[ni][k2] = __builtin_bit_cast(bf16x8, hu);
        bl[ni][k2] = __builtin_bit_cast(bf16x8, lu);
      }
    // ---- MFMA: 3-term emulated fp32 into per-l accumulator P ----
#pragma unroll
    for (int k2 = 0; k2 < 2; ++k2) {
      int kb = k2 * 32 + q * 8;
#pragma unroll
      for (int mi = 0; mi < 4; ++mi) {
        int ix = swzA(wm * 64 + mi * 16 + fr, kb);
        bf16x8 ah = *(const bf16x8*)&Ah[ix];
        bf16x8 al = *(const bf16x8*)&Al[ix];
#pragma unroll
        for (int ni = 0; ni < 2; ++ni) {
          P[mi][ni] = __builtin_amdgcn_mfma_f32_16x16x32_bf16(ah, bh[ni][k2], P[mi][ni], 0, 0, 0);
          P[mi][ni] = __builtin_amdgcn_mfma_f32_16x16x32_bf16(ah, bl[ni][k2], P[mi][ni], 0, 0, 0);
          P[mi][ni] = __builtin_amdgcn_mfma_f32_16x16x32_bf16(al, bh[ni][k2], P[mi][ni], 0, 0, 0);
        }
      }
    }
    // ---- per-l scale epilogue: R += sw[b] * P (fp32) ----
    if (jci == 3) {
#pragma unroll
      for (int mi = 0; mi < 4; ++mi) {
        f32x4 s4 = *(const f32x4*)&sw[wm * 64 + mi * 16 + q * 4];
#pragma unroll
        for (int ni = 0; ni < 2; ++ni) {
          R[mi][ni] += s4 * P[mi][ni];
          P[mi][ni] = (f32x4)0.f;
        }
      }
    }
    __syncthreads();  // readers done before next DMA overwrites
  }

  // ---- epilogue: write partials ----
  float* pout = part + ((size_t)sp * NS + s) * (B * D);
#pragma unroll
  for (int mi = 0; mi < 4; ++mi)
#pragma unroll
    for (int ni = 0; ni < 2; ++ni) {
      int col = i0 + wn * 32 + ni * 16 + fr;
#pragma unroll
      for (int r = 0; r < 4; ++r) {
        int bb = wm * 64 + mi * 16 + q * 4 + r;
        pout[(size_t)bb * D + col] = R[mi][ni][r];
      }
    }
}

// ---------------------------------------------------------------------------
// K3R: u_slots[b,s,i] = (sum_sp part[sp,s,b,i]) / weighted_c[b,s]
// ---------------------------------------------------------------------------
__global__ __launch_bounds__(256) void k3r_reduce(
    const float* __restrict__ part, const float* __restrict__ wc,
    float* __restrict__ u_slots, int nsplit) {
  int idx = blockIdx.x * 256 + threadIdx.x;  // over (s,b,i)
  int i  = idx & (D - 1);
  int sb = idx >> 8;
  int b  = sb & (B - 1);
  int s  = sb >> 7;
  float v = 0.f;
  for (int sp = 0; sp < nsplit; ++sp)
    v += part[(size_t)sp * (NS * B * D) + idx];
  u_slots[((size_t)b * NS + s) * D + i] = v / wc[b * NS + s];
}

// ---------------------------------------------------------------------------
// K4: per (b,s): logits2 = w_route_si[s] . u_slots[b,s]; softmax over NI;
//     w2 = c_si * a_slots.
// ---------------------------------------------------------------------------
__global__ __launch_bounds__(64) void k4_route_si(
    const float* __restrict__ u_slots, const float* __restrict__ wr_si,
    const float* __restrict__ a_slots, float* __restrict__ w2) {
  int bs = blockIdx.x;
  int s  = bs & (NS - 1);
  int lane = threadIdx.x;
  __shared__ float su[D];
  __shared__ float slog[NI];
#pragma unroll
  for (int jj = 0; jj < 4; ++jj) su[lane + jj * 64] = u_slots[bs * D + lane + jj * 64];
  __syncthreads();
  for (int i = 0; i < NI; ++i) {
    const float* w = wr_si + (s * NI + i) * D;
    float p = 0.f;
#pragma unroll
    for (int jj = 0; jj < 4; ++jj) {
      int j = lane + jj * 64;
      p = fmaf(w[j], su[j], p);
    }
    p = wave_reduce_sum(p);
    if (lane == 0) slog[i] = p;
  }
  __syncthreads();
  float v = (lane < NI) ? slog[lane] : -INFINITY;
  float m = wave_reduce_max(v);
  float e = (lane < NI) ? __expf(v - m) : 0.f;
  float ssum = wave_reduce_sum(e);
  if (lane < NI) w2[bs * NI + lane] = (e / ssum) * a_slots[bs];
}

// ---------------------------------------------------------------------------
// K5: wc2[b,i] = sum_s w2; a_intents = wc2 / sum_s a_slots.
// ---------------------------------------------------------------------------
__global__ __launch_bounds__(64) void k5_intents_agg(
    const float* __restrict__ w2, const float* __restrict__ a_slots,
    float* __restrict__ wc2, float* __restrict__ a_intents) {
  int b = blockIdx.x;
  int lane = threadIdx.x;
  float as = (lane < NS) ? a_slots[b * NS + lane] : 0.f;
  float sas = wave_reduce_sum(as);
  if (lane < NI) {
    float wc = 0.f;
    for (int s = 0; s < NS; ++s) wc += w2[(b * NS + s) * NI + lane];
    wc2[b * NI + lane] = wc;
    a_intents[b * NI + lane] = wc / sas;
  }
}

// ---------------------------------------------------------------------------
// K6: Wsum[s,i,k] = sum_j w_pose_si[s,i,j,k] (float4-vectorized over k).
// ---------------------------------------------------------------------------
__global__ __launch_bounds__(256) void k6_wsum(
    const float* __restrict__ wps, float* __restrict__ wsum) {
  __shared__ float red[4][D];
  int si = blockIdx.x;
  int t  = threadIdx.x;
  int k4 = (t & 63) * 4;
  int jg = t >> 6;
  const float* base = wps + (size_t)si * D * D;
  float4 acc = {0.f, 0.f, 0.f, 0.f};
  for (int j = jg; j < D; j += 4) {
    float4 v = *(const float4*)(base + (size_t)j * D + k4);
    acc.x += v.x; acc.y += v.y; acc.z += v.z; acc.w += v.w;
  }
  *(float4*)&red[jg][k4] = acc;
  __syncthreads();
  wsum[si * D + t] = (red[0][t] + red[1][t]) + (red[2][t] + red[3][t]);
}

// ---------------------------------------------------------------------------
// K7: u_intents[b,i,k] = sum_s w2[b,s,i]*u_slots[b,s,k]*Wsum[s,i,k] / wc2[b,i]
// ---------------------------------------------------------------------------
__global__ __launch_bounds__(256) void k7_uintents(
    const float* __restrict__ u_slots, const float* __restrict__ w2,
    const float* __restrict__ wsum, const float* __restrict__ wc2,
    float* __restrict__ u_intents) {
  int bi = blockIdx.x;
  int b = bi >> 4, i = bi & (NI - 1);
  int k = threadIdx.x;
  float acc = 0.f;
  for (int s = 0; s < NS; ++s) {
    float w = w2[(b * NS + s) * NI + i];
    acc = fmaf(w * u_slots[(b * NS + s) * D + k], wsum[(s * NI + i) * D + k], acc);
  }
  u_intents[bi * D + k] = acc / wc2[bi];
}

// ---------------------------------------------------------------------------
extern "C" void kernel_launch(void* const* d_in, const int* in_sizes, int n_in,
                              void* d_out, int out_size, void* d_ws, size_t ws_size,
                              hipStream_t stream) {
  const float* tf    = (const float*)d_in[0];  // (B,L,D)
  const float* wr_ws = (const float*)d_in[1];  // (L,NS,D)
  const float* wp_ws = (const float*)d_in[2];  // (L,NS,D,D)
  const float* wr_si = (const float*)d_in[3];  // (NS,NI,D)
  const float* wp_si = (const float*)d_in[4];  // (NS,NI,D,D)

  float* out       = (float*)d_out;
  float* a_slots   = out;                      // B*NS
  float* u_slots   = a_slots + B * NS;         // B*NS*D
  float* a_intents = u_slots + B * NS * D;     // B*NI
  float* u_intents = a_intents + B * NI;       // B*NI*D

  float* ws         = (float*)d_ws;
  float* wlsT       = ws;                      // L*NS*B  = 262144
  float* a_words    = wlsT + L * NS * B;       // B*L     = 8192
  float* weighted_c = a_words + B * L;         // B*NS    = 4096
  float* w2         = weighted_c + B * NS;     // B*NS*NI = 65536
  float* wc2        = w2 + B * NS * NI;        // B*NI    = 2048
  float* wsum       = wc2 + B * NI;            // NS*NI*D = 131072
  // bf16 hi/lo swizzled images of tf: 64*4 tiles x 8192 ushorts each
  ushort* xh        = (ushort*)(wsum + NS * NI * D);    // 2,097,152 ushorts
  ushort* xl        = xh + (size_t)L * 4 * 8192;        // 2,097,152 ushorts
  float*  part      = (float*)(xl + (size_t)L * 4 * 8192);  // nsplit*NS*B*D

  const size_t base_f  = 473088 + 1048576 * 2 / 2 * 2;  // pre-part floats (incl. images)
  const size_t chunk_f = (size_t)NS * B * D;             // 1,048,576 per split
  size_t avail_f = ws_size / sizeof(float);
  int nsplit = 1;
  if (avail_f >= base_f + 4 * chunk_f)      nsplit = 4;
  else if (avail_f >= base_f + 2 * chunk_f) nsplit = 2;

  kx_split<<<L * 4, 256, 0, stream>>>(tf, xh, xl);
  k1_route_words<<<B * L, 256, 0, stream>>>(tf, wr_ws, wlsT, a_words);
  k2_slots_agg<<<B, 64, 0, stream>>>(wlsT, a_words, weighted_c, a_slots);
  k3_mfma<<<NS * 4 * nsplit, 256, 0, stream>>>(xh, xl, wp_ws, wlsT, part, nsplit);
  k3r_reduce<<<(NS * B * D) / 256, 256, 0, stream>>>(part, weighted_c, u_slots, nsplit);
  k6_wsum<<<NS * NI, 256, 0, stream>>>(wp_si, wsum);
  k4_route_si<<<B * NS, 64, 0, stream>>>(u_slots, wr_si, a_slots, w2);
  k5_intents_agg<<<B, 64, 0, stream>>>(w2, a_slots, wc2, a_intents);
  k7_uintents<<<B * NI, 256, 0, stream>>>(u_slots, w2, wsum, wc2, u_intents);
}